// Round 4
// baseline (305.590 us; speedup 1.0000x reference)
//
#include <hip/hip_runtime.h>
#include <math.h>

#define D_X      1024
#define D_TEXT   768
#define FDIM     1792
#define BATCH    256
#define M_EXP    16
#define HW_TOT   1024   // 32*32

// Output layout (flat f32): gates[4096] | moe_loss[1] | probs[4096] | top_idx[512]
#define OUT_GATES 0
#define OUT_LOSS  4096
#define OUT_PROBS 4097
#define OUT_IDX   8193

#define NBLK_POOL (BATCH * D_X / 4)   // 65536
#define NBLK_COPY 192

// ---------------------------------------------------------------------------
// Kernel 1: mean-pool x (B,1024,32,32) -> fused[:, :1024]  (one wave per row)
//           + copy degraded (256,768) -> fused[:, 1024:]   (tail blocks)
// (identical to the 250-us R2 version)
// ---------------------------------------------------------------------------
__global__ __launch_bounds__(256) void pool_copy_kernel(const float* __restrict__ x,
                                                        const float* __restrict__ deg,
                                                        float* __restrict__ fused) {
    const int blk = blockIdx.x;
    if (blk < NBLK_POOL) {
        const int gtid = blk * 256 + threadIdx.x;
        const int row  = gtid >> 6;            // (b,c) id in [0, BATCH*D_X)
        const int lane = gtid & 63;
        const float4* xr = reinterpret_cast<const float4*>(x + (size_t)row * HW_TOT);
        float s = 0.0f;
#pragma unroll
        for (int k = 0; k < 4; ++k) {
            float4 v = xr[k * 64 + lane];
            s += v.x + v.y + v.z + v.w;
        }
#pragma unroll
        for (int off = 32; off > 0; off >>= 1) s += __shfl_xor(s, off, 64);
        if (lane == 0) {
            const int b = row >> 10;
            const int c = row & 1023;
            fused[(size_t)b * FDIM + c] = s * (1.0f / 1024.0f);
        }
    } else {
        const int tid = (blk - NBLK_POOL) * 256 + threadIdx.x;  // float4 id
        if (tid < BATCH * (D_TEXT / 4)) {
            const int b  = tid / (D_TEXT / 4);
            const int j4 = tid % (D_TEXT / 4);
            const float4 v = reinterpret_cast<const float4*>(deg)[tid];
            reinterpret_cast<float4*>(fused)[(size_t)b * (FDIM / 4) + (D_X / 4) + j4] = v;
        }
    }
}

// ---------------------------------------------------------------------------
// Kernel 2: K-split fp32 GEMM partials.
// pact[z][m][n] = fused[m, kz:kz+224] @ W[kz:kz+224, n]
// 128m x 128n tile, 256 threads (4 waves), per-thread 8x8 (two 4-strips),
// BK=32, register-staged double-buffered LDS (exactly 64 KB), grid (2,14,8).
// Per-tile compute per wave = 32k*64fma*2cy = 4096 cy >> load latency.
// LDS read: float4 both sides, 2-way bank aliasing only (free).
// ---------------------------------------------------------------------------
#define TM 128
#define TN 128
#define BK 32
#define KSPLIT 8
#define KCH (FDIM / KSPLIT)     // 224
#define NIT (KCH / BK)          // 7

#define LOADA(k0)                                                                              \
    pa[0] = *reinterpret_cast<const float4*>(A + (size_t)(m0 + ar) * FDIM + (k0) + ak4);       \
    pa[1] = *reinterpret_cast<const float4*>(A + (size_t)(m0 + ar + 32) * FDIM + (k0) + ak4);  \
    pa[2] = *reinterpret_cast<const float4*>(A + (size_t)(m0 + ar + 64) * FDIM + (k0) + ak4);  \
    pa[3] = *reinterpret_cast<const float4*>(A + (size_t)(m0 + ar + 96) * FDIM + (k0) + ak4);

#define LOADW(k0)                                                                              \
    pw[0] = *reinterpret_cast<const float4*>(W + (size_t)((k0) + wr) * FDIM + n0 + wc4);       \
    pw[1] = *reinterpret_cast<const float4*>(W + (size_t)((k0) + wr + 8) * FDIM + n0 + wc4);   \
    pw[2] = *reinterpret_cast<const float4*>(W + (size_t)((k0) + wr + 16) * FDIM + n0 + wc4);  \
    pw[3] = *reinterpret_cast<const float4*>(W + (size_t)((k0) + wr + 24) * FDIM + n0 + wc4);

#define STOREA(b)                                                                 \
    _Pragma("unroll")                                                             \
    for (int q = 0; q < 4; ++q) {                                                 \
        As[b][ak4 + q][ar]      = ((const float*)&pa[0])[q];                      \
        As[b][ak4 + q][ar + 32] = ((const float*)&pa[1])[q];                      \
        As[b][ak4 + q][ar + 64] = ((const float*)&pa[2])[q];                      \
        As[b][ak4 + q][ar + 96] = ((const float*)&pa[3])[q];                      \
    }

#define STOREW(b)                                                                 \
    *reinterpret_cast<float4*>(&Ws[b][wr][wc4])      = pw[0];                     \
    *reinterpret_cast<float4*>(&Ws[b][wr + 8][wc4])  = pw[1];                     \
    *reinterpret_cast<float4*>(&Ws[b][wr + 16][wc4]) = pw[2];                     \
    *reinterpret_cast<float4*>(&Ws[b][wr + 24][wc4]) = pw[3];

__global__ __launch_bounds__(256) void gemm_split_kernel(const float* __restrict__ A,
                                                         const float* __restrict__ W,
                                                         float* __restrict__ pact) {
    __shared__ float As[2][BK][TM];   // [k][m] transposed; 32 KB
    __shared__ float Ws[2][BK][TN];   // [k][n];            32 KB

    const int tid = threadIdx.x;
    const int tx  = tid & 15;             // 16 n-groups
    const int ty  = tid >> 4;             // 16 m-groups
    const int m0  = blockIdx.x * TM;
    const int n0  = blockIdx.y * TN;
    const int kz  = blockIdx.z * KCH;

    // A staging: 128 rows x 32 k = 1024 float4, 4/thread
    const int ar  = tid >> 3;             // rows ar, +32, +64, +96
    const int ak4 = (tid & 7) * 4;
    // W staging: 32 k x 128 n = 1024 float4, 4/thread
    const int wr  = tid >> 5;             // k rows wr, +8, +16, +24
    const int wc4 = (tid & 31) * 4;

    float4 pa[4], pw[4];

    LOADA(kz); LOADW(kz);
    STOREA(0); STOREW(0);
    LOADA(kz + BK); LOADW(kz + BK);
    __syncthreads();

    float acc[8][8] = {};
    int cur = 0;

    for (int t = 0; t < NIT; ++t) {
#pragma unroll
        for (int kk = 0; kk < BK; ++kk) {
            const float4 a0 = *reinterpret_cast<const float4*>(&As[cur][kk][ty * 4]);
            const float4 a1 = *reinterpret_cast<const float4*>(&As[cur][kk][64 + ty * 4]);
            const float4 w0 = *reinterpret_cast<const float4*>(&Ws[cur][kk][tx * 4]);
            const float4 w1 = *reinterpret_cast<const float4*>(&Ws[cur][kk][64 + tx * 4]);
            const float av[8] = {a0.x, a0.y, a0.z, a0.w, a1.x, a1.y, a1.z, a1.w};
            const float wv[8] = {w0.x, w0.y, w0.z, w0.w, w1.x, w1.y, w1.z, w1.w};
#pragma unroll
            for (int i = 0; i < 8; ++i)
#pragma unroll
                for (int j = 0; j < 8; ++j)
                    acc[i][j] = fmaf(av[i], wv[j], acc[i][j]);
        }
        if (t < NIT - 1) {
            const int nxt = cur ^ 1;
            STOREA(nxt); STOREW(nxt);
            if (t < NIT - 2) {
                const int k0 = kz + (t + 2) * BK;
                LOADA(k0); LOADW(k0);
            }
            __syncthreads();
            cur = nxt;
        }
    }

    // write 8 rows x (two float4 col-strips)
#pragma unroll
    for (int i = 0; i < 8; ++i) {
        const int m = m0 + ((i < 4) ? (ty * 4 + i) : (64 + ty * 4 + (i - 4)));
        float* o = pact + ((size_t)blockIdx.z * BATCH + m) * FDIM + n0;
        float4 v0, v1;
        v0.x = acc[i][0]; v0.y = acc[i][1]; v0.z = acc[i][2]; v0.w = acc[i][3];
        v1.x = acc[i][4]; v1.y = acc[i][5]; v1.z = acc[i][6]; v1.w = acc[i][7];
        *reinterpret_cast<float4*>(o + tx * 4)      = v0;
        *reinterpret_cast<float4*>(o + 64 + tx * 4) = v1;
    }
}

// ---------------------------------------------------------------------------
// Kernel 3: act = gelu(sum_z pact[z] + bias) tile -> LDS, then gate partials
//           part[nb][m][e] = sum_{n in block} act[m][n] * wg[n][e]
// ---------------------------------------------------------------------------
#define BM2 32
#define BN2 64

__global__ __launch_bounds__(256) void reduce_gate_kernel(const float* __restrict__ pact,
                                                          const float* __restrict__ bias,
                                                          const float* __restrict__ wg,
                                                          float* __restrict__ part) {
    __shared__ float actS[BM2][BN2 + 1];
    __shared__ float wgs[BN2][M_EXP];

    const int tid = threadIdx.x;
    const int m0 = blockIdx.x * BM2;
    const int n0 = blockIdx.y * BN2;

    // wg slab: 64 rows x 16 = 256 float4
    {
        const int r  = tid >> 2;
        const int c4 = (tid & 3) * 4;
        *reinterpret_cast<float4*>(&wgs[r][c4]) =
            *reinterpret_cast<const float4*>(wg + (size_t)(n0 + r) * M_EXP + c4);
    }

    const int row = tid >> 3;            // 0..31
    const int c8  = (tid & 7) * 8;       // 0..56
    const size_t base = (size_t)(m0 + row) * FDIM + n0 + c8;
#pragma unroll
    for (int h = 0; h < 2; ++h) {
        const float4 bb = *reinterpret_cast<const float4*>(bias + n0 + c8 + h * 4);
        float vv[4] = {bb.x, bb.y, bb.z, bb.w};
#pragma unroll
        for (int z = 0; z < KSPLIT; ++z) {
            const float4 p = *reinterpret_cast<const float4*>(
                pact + (size_t)z * BATCH * FDIM + base + h * 4);
            vv[0] += p.x; vv[1] += p.y; vv[2] += p.z; vv[3] += p.w;
        }
#pragma unroll
        for (int j = 0; j < 4; ++j)
            actS[row][c8 + h * 4 + j] =
                vv[j] * 0.5f * (1.0f + erff(vv[j] * 0.70710678118654752440f));
    }
    __syncthreads();

    const int pm = tid >> 3;             // 0..31
    const int pe = (tid & 7) * 2;        // 0,2,..,14
    float s0 = 0.0f, s1 = 0.0f;
#pragma unroll
    for (int n = 0; n < BN2; ++n) {
        const float a = actS[pm][n];
        s0 = fmaf(a, wgs[n][pe], s0);
        s1 = fmaf(a, wgs[n][pe + 1], s1);
    }
    float* pr = part + ((size_t)blockIdx.y * BATCH + m0 + pm) * M_EXP + pe;
    pr[0] = s0;
    pr[1] = s1;
}

// ---------------------------------------------------------------------------
// Kernel 4: finalize — sum 28 partials (fixed order), softmax, top-2 routing.
// ---------------------------------------------------------------------------
#define NNB (FDIM / BN2)   // 28

__global__ __launch_bounds__(64) void finalize_kernel(const float* __restrict__ part,
                                                      float* __restrict__ out) {
    const int b = blockIdx.x * 64 + threadIdx.x;   // 0..255

    float l[M_EXP];
#pragma unroll
    for (int m = 0; m < M_EXP; ++m) l[m] = 0.0f;

    for (int nb = 0; nb < NNB; ++nb) {
        const float4* pr = reinterpret_cast<const float4*>(part + ((size_t)nb * BATCH + b) * M_EXP);
#pragma unroll
        for (int q = 0; q < 4; ++q) {
            const float4 v = pr[q];
            l[q * 4 + 0] += v.x;
            l[q * 4 + 1] += v.y;
            l[q * 4 + 2] += v.z;
            l[q * 4 + 3] += v.w;
        }
    }

    float mx = l[0];
#pragma unroll
    for (int m = 1; m < M_EXP; ++m) mx = fmaxf(mx, l[m]);
    float e[M_EXP], s = 0.0f;
#pragma unroll
    for (int m = 0; m < M_EXP; ++m) { e[m] = expf(l[m] - mx); s += e[m]; }
    const float inv = 1.0f / s;
#pragma unroll
    for (int m = 0; m < M_EXP; ++m) out[OUT_PROBS + b * M_EXP + m] = e[m] * inv;

    int i0 = 0; float v0 = l[0];
#pragma unroll
    for (int m = 1; m < M_EXP; ++m) if (l[m] > v0) { v0 = l[m]; i0 = m; }
    int i1 = -1; float v1 = -INFINITY;
#pragma unroll
    for (int m = 0; m < M_EXP; ++m) if (m != i0 && l[m] > v1) { v1 = l[m]; i1 = m; }

    const float t = expf(v1 - v0);
    const float g0 = 1.0f / (1.0f + t);
    const float g1 = t * g0;

#pragma unroll
    for (int m = 0; m < M_EXP; ++m) out[OUT_GATES + b * M_EXP + m] = 0.0f;
    out[OUT_GATES + b * M_EXP + i0] = g0;
    out[OUT_GATES + b * M_EXP + i1] = g1;

    out[OUT_IDX + b * 2 + 0] = (float)i0;
    out[OUT_IDX + b * 2 + 1] = (float)i1;

    if (b == 0) out[OUT_LOSS] = 0.0f;
}

// ---------------------------------------------------------------------------
extern "C" void kernel_launch(void* const* d_in, const int* in_sizes, int n_in,
                              void* d_out, int out_size, void* d_ws, size_t ws_size,
                              hipStream_t stream) {
    const float* x        = (const float*)d_in[0];
    const float* degraded = (const float*)d_in[1];
    const float* w_fusion = (const float*)d_in[2];
    const float* b_fusion = (const float*)d_in[3];
    const float* w_gate   = (const float*)d_in[4];
    float* out = (float*)d_out;

    float* fused = (float*)d_ws;                              // 256*1792 f32       (1.84 MB)
    float* pact  = fused + (size_t)BATCH * FDIM;              // 8*256*1792 f32     (14.7 MB)
    float* part  = pact + (size_t)KSPLIT * BATCH * FDIM;      // 28*256*16 f32      (0.46 MB)

    // 1) pool + degraded copy (one-shot, proven)
    pool_copy_kernel<<<NBLK_POOL + NBLK_COPY, 256, 0, stream>>>(x, degraded, fused);

    // 2) K-split fusion GEMM partials: grid (2, 14, 8), 256 threads
    gemm_split_kernel<<<dim3(BATCH / TM, FDIM / TN, KSPLIT), 256, 0, stream>>>(fused, w_fusion, pact);

    // 3) reduce + bias + gelu + gate partials: grid (8, 28)
    reduce_gate_kernel<<<dim3(BATCH / BM2, FDIM / BN2), 256, 0, stream>>>(pact, b_fusion, w_gate, part);

    // 4) finalize
    finalize_kernel<<<BATCH / 64, 64, 0, stream>>>(part, out);
}

// Round 5
// 235.247 us; speedup vs baseline: 1.2990x; 1.2990x over previous
//
#include <hip/hip_runtime.h>
#include <math.h>

#define D_X      1024
#define D_TEXT   768
#define FDIM     1792
#define BATCH    256
#define M_EXP    16
#define HW_TOT   1024   // 32*32

// Output layout (flat f32): gates[4096] | moe_loss[1] | probs[4096] | top_idx[512]
#define OUT_GATES 0
#define OUT_LOSS  4096
#define OUT_PROBS 4097
#define OUT_IDX   8193

// ---------------------------------------------------------------------------
// Kernel 1 (role-split):
//   blocks [0, 224):      deg-GEMM  pact2[m][n] = degraded[m,:] @ W[1024:,:n]
//                         (no pool dependency -> runs hidden under the pool)
//   blocks [224, 65760):  mean-pool x (B,1024,32,32) -> fused dense (256,1024)
// ---------------------------------------------------------------------------
#define NBLK_DGEMM 224
#define NBLK_POOL  (BATCH * D_X / 4)   // 65536

__global__ __launch_bounds__(256) void pool_deggemm_kernel(const float* __restrict__ x,
                                                           const float* __restrict__ deg,
                                                           const float* __restrict__ W,
                                                           float* __restrict__ fused,
                                                           float* __restrict__ pact2) {
    __shared__ float As1[32][33];   // deg tile, transposed [k][m]
    __shared__ float Ws1[32][64];   // W tile [k][n]

    const int bid = blockIdx.x;
    const int tid = threadIdx.x;

    if (bid >= NBLK_DGEMM) {
        // ---- pool path: one wave per (b,c) row of 1024 contiguous floats ----
        const int gtid = (bid - NBLK_DGEMM) * 256 + tid;
        const int row  = gtid >> 6;            // 0 .. 262143
        const int lane = gtid & 63;
        const float4* xr = reinterpret_cast<const float4*>(x + (size_t)row * HW_TOT);
        float s = 0.0f;
#pragma unroll
        for (int k = 0; k < 4; ++k) {
            float4 v = xr[k * 64 + lane];
            s += v.x + v.y + v.z + v.w;
        }
#pragma unroll
        for (int off = 32; off > 0; off >>= 1) s += __shfl_xor(s, off, 64);
        if (lane == 0) fused[row] = s * (1.0f / 1024.0f);
        return;
    }

    // ---- deg-GEMM path: 32m x 64n tile, BK=32, single-buffered, 24 iters ----
    const int mb = bid / 28;
    const int nb = bid % 28;
    const int m0 = mb * 32;
    const int n0 = nb * 64;

    const int tx = tid & 15;        // n-groups of 4
    const int ty = tid >> 4;        // m-groups of 2

    const int ar  = tid >> 3;       // A row 0..31
    const int ak4 = (tid & 7) * 4;  // A k-col
    const int wk  = tid >> 4;       // W k-row (+16 for second)
    const int wc4 = (tid & 15) * 4; // W n-col

    float acc[2][4] = {};

    for (int k0 = 0; k0 < D_TEXT; k0 += 32) {
        __syncthreads();
        {
            const float4 a = *reinterpret_cast<const float4*>(
                deg + (size_t)(m0 + ar) * D_TEXT + k0 + ak4);
            As1[ak4 + 0][ar] = a.x; As1[ak4 + 1][ar] = a.y;
            As1[ak4 + 2][ar] = a.z; As1[ak4 + 3][ar] = a.w;
            *reinterpret_cast<float4*>(&Ws1[wk][wc4]) =
                *reinterpret_cast<const float4*>(W + (size_t)(D_X + k0 + wk) * FDIM + n0 + wc4);
            *reinterpret_cast<float4*>(&Ws1[wk + 16][wc4]) =
                *reinterpret_cast<const float4*>(W + (size_t)(D_X + k0 + wk + 16) * FDIM + n0 + wc4);
        }
        __syncthreads();
#pragma unroll
        for (int kk = 0; kk < 32; ++kk) {
            const float2 a = *reinterpret_cast<const float2*>(&As1[kk][ty * 2]);
            const float4 w = *reinterpret_cast<const float4*>(&Ws1[kk][tx * 4]);
            acc[0][0] = fmaf(a.x, w.x, acc[0][0]);
            acc[0][1] = fmaf(a.x, w.y, acc[0][1]);
            acc[0][2] = fmaf(a.x, w.z, acc[0][2]);
            acc[0][3] = fmaf(a.x, w.w, acc[0][3]);
            acc[1][0] = fmaf(a.y, w.x, acc[1][0]);
            acc[1][1] = fmaf(a.y, w.y, acc[1][1]);
            acc[1][2] = fmaf(a.y, w.z, acc[1][2]);
            acc[1][3] = fmaf(a.y, w.w, acc[1][3]);
        }
    }

#pragma unroll
    for (int i = 0; i < 2; ++i) {
        float4 v;
        v.x = acc[i][0]; v.y = acc[i][1]; v.z = acc[i][2]; v.w = acc[i][3];
        *reinterpret_cast<float4*>(pact2 + (size_t)(m0 + ty * 2 + i) * FDIM + n0 + tx * 4) = v;
    }
}

// ---------------------------------------------------------------------------
// Kernel 2: act = gelu(fused @ W[:1024] + pact2 + bias) tile, gate partials.
// A: (256,1024) rm dense; W: (1792,1792) rm; identical inner loop to the
// proven R2 kernel, K-range reduced to [0,1024) with acc init from pact2.
// ---------------------------------------------------------------------------
#define BM 32
#define BN 64
#define BK 64
#define KDIM D_X            // 1024
#define NITER (KDIM / BK)   // 16

#define LOADA(k0)                                                                     \
    pa0 = *reinterpret_cast<const float4*>(A + (size_t)(m0 + ar) * KDIM + (k0) + ak4);       \
    pa1 = *reinterpret_cast<const float4*>(A + (size_t)(m0 + ar + 16) * KDIM + (k0) + ak4);

#define LOADW(k0)                                                                     \
    pw0 = *reinterpret_cast<const float4*>(W + (size_t)((k0) + wr0) * FDIM + n0 + wc4);      \
    pw1 = *reinterpret_cast<const float4*>(W + (size_t)((k0) + wr0 + 16) * FDIM + n0 + wc4); \
    pw2 = *reinterpret_cast<const float4*>(W + (size_t)((k0) + wr0 + 32) * FDIM + n0 + wc4); \
    pw3 = *reinterpret_cast<const float4*>(W + (size_t)((k0) + wr0 + 48) * FDIM + n0 + wc4);

#define STOREA(buf)                                                                   \
    As[buf][ak4 + 0][ar] = pa0.x; As[buf][ak4 + 1][ar] = pa0.y;                       \
    As[buf][ak4 + 2][ar] = pa0.z; As[buf][ak4 + 3][ar] = pa0.w;                       \
    As[buf][ak4 + 0][ar + 16] = pa1.x; As[buf][ak4 + 1][ar + 16] = pa1.y;             \
    As[buf][ak4 + 2][ar + 16] = pa1.z; As[buf][ak4 + 3][ar + 16] = pa1.w;

#define STOREW(buf)                                                                   \
    *reinterpret_cast<float4*>(&Ws[buf][wr0][wc4])      = pw0;                        \
    *reinterpret_cast<float4*>(&Ws[buf][wr0 + 16][wc4]) = pw1;                        \
    *reinterpret_cast<float4*>(&Ws[buf][wr0 + 32][wc4]) = pw2;                        \
    *reinterpret_cast<float4*>(&Ws[buf][wr0 + 48][wc4]) = pw3;

__global__ __launch_bounds__(256) void gemm_gate_kernel(const float* __restrict__ A,
                                                        const float* __restrict__ W,
                                                        const float* __restrict__ pact2,
                                                        const float* __restrict__ bias,
                                                        const float* __restrict__ wg,
                                                        float* __restrict__ part) {
    __shared__ float As[2][BK][BM + 1];
    __shared__ float Ws[2][BK][BN];
    __shared__ float wgs[BN][M_EXP];
    __shared__ float actS[BM][BN + 1];

    const int tid = threadIdx.x;
    const int tx = tid & 15;
    const int ty = tid >> 4;
    const int m0 = blockIdx.x * BM;
    const int n0 = blockIdx.y * BN;

    // wg slab: 64 rows x 16 = 256 float4
    {
        const int r  = tid >> 2;
        const int c4 = (tid & 3) * 4;
        *reinterpret_cast<float4*>(&wgs[r][c4]) =
            *reinterpret_cast<const float4*>(wg + (size_t)(n0 + r) * M_EXP + c4);
    }

    const int ar  = tid >> 4;
    const int ak4 = (tid & 15) * 4;
    const int wr0 = tid >> 4;
    const int wc4 = (tid & 15) * 4;

    float4 pa0, pa1, pw0, pw1, pw2, pw3;

    LOADA(0); LOADW(0);
    STOREA(0); STOREW(0);
    LOADA(BK); LOADW(BK);

    // acc init from deg-GEMM partial (written by kernel 1, visible here)
    float acc[2][4];
    {
        const float4 i0 = *reinterpret_cast<const float4*>(
            pact2 + (size_t)(m0 + ty * 2) * FDIM + n0 + tx * 4);
        const float4 i1 = *reinterpret_cast<const float4*>(
            pact2 + (size_t)(m0 + ty * 2 + 1) * FDIM + n0 + tx * 4);
        acc[0][0] = i0.x; acc[0][1] = i0.y; acc[0][2] = i0.z; acc[0][3] = i0.w;
        acc[1][0] = i1.x; acc[1][1] = i1.y; acc[1][2] = i1.z; acc[1][3] = i1.w;
    }
    __syncthreads();

    int cur = 0;
    for (int t = 0; t < NITER; ++t) {
#pragma unroll
        for (int kk = 0; kk < BK; ++kk) {
            const float2 a = *reinterpret_cast<const float2*>(&As[cur][kk][ty * 2]);
            const float4 w = *reinterpret_cast<const float4*>(&Ws[cur][kk][tx * 4]);
            acc[0][0] = fmaf(a.x, w.x, acc[0][0]);
            acc[0][1] = fmaf(a.x, w.y, acc[0][1]);
            acc[0][2] = fmaf(a.x, w.z, acc[0][2]);
            acc[0][3] = fmaf(a.x, w.w, acc[0][3]);
            acc[1][0] = fmaf(a.y, w.x, acc[1][0]);
            acc[1][1] = fmaf(a.y, w.y, acc[1][1]);
            acc[1][2] = fmaf(a.y, w.z, acc[1][2]);
            acc[1][3] = fmaf(a.y, w.w, acc[1][3]);
        }
        if (t < NITER - 1) {
            const int nxt = cur ^ 1;
            STOREA(nxt); STOREW(nxt);
            if (t < NITER - 2) {
                const int k0 = (t + 2) * BK;
                LOADA(k0); LOADW(k0);
            }
            __syncthreads();
            cur = nxt;
        }
    }

    // epilogue: bias + exact GELU -> actS
#pragma unroll
    for (int i = 0; i < 2; ++i) {
        const int m = ty * 2 + i;
#pragma unroll
        for (int j = 0; j < 4; ++j) {
            const int n = tx * 4 + j;
            const float v = acc[i][j] + bias[n0 + n];
            actS[m][n] = v * 0.5f * (1.0f + erff(v * 0.70710678118654752440f));
        }
    }
    __syncthreads();

    // gate partials: 32 rows x 16 experts, 2 per thread
    const int pm = tid >> 3;
    const int pe = (tid & 7) * 2;
    float s0 = 0.0f, s1 = 0.0f;
#pragma unroll
    for (int n = 0; n < BN; ++n) {
        const float a = actS[pm][n];
        s0 = fmaf(a, wgs[n][pe], s0);
        s1 = fmaf(a, wgs[n][pe + 1], s1);
    }
    float* pr = part + ((size_t)blockIdx.y * BATCH + m0 + pm) * M_EXP + pe;
    pr[0] = s0;
    pr[1] = s1;
}

// ---------------------------------------------------------------------------
// Kernel 3: finalize — sum 28 partials (fixed order), softmax, top-2 routing.
// ---------------------------------------------------------------------------
#define NNB (FDIM / BN)   // 28

__global__ __launch_bounds__(64) void finalize_kernel(const float* __restrict__ part,
                                                      float* __restrict__ out) {
    const int b = blockIdx.x * 64 + threadIdx.x;   // 0..255

    float l[M_EXP];
#pragma unroll
    for (int m = 0; m < M_EXP; ++m) l[m] = 0.0f;

    for (int nb = 0; nb < NNB; ++nb) {
        const float4* pr = reinterpret_cast<const float4*>(part + ((size_t)nb * BATCH + b) * M_EXP);
#pragma unroll
        for (int q = 0; q < 4; ++q) {
            const float4 v = pr[q];
            l[q * 4 + 0] += v.x;
            l[q * 4 + 1] += v.y;
            l[q * 4 + 2] += v.z;
            l[q * 4 + 3] += v.w;
        }
    }

    float mx = l[0];
#pragma unroll
    for (int m = 1; m < M_EXP; ++m) mx = fmaxf(mx, l[m]);
    float e[M_EXP], s = 0.0f;
#pragma unroll
    for (int m = 0; m < M_EXP; ++m) { e[m] = expf(l[m] - mx); s += e[m]; }
    const float inv = 1.0f / s;
#pragma unroll
    for (int m = 0; m < M_EXP; ++m) out[OUT_PROBS + b * M_EXP + m] = e[m] * inv;

    int i0 = 0; float v0 = l[0];
#pragma unroll
    for (int m = 1; m < M_EXP; ++m) if (l[m] > v0) { v0 = l[m]; i0 = m; }
    int i1 = -1; float v1 = -INFINITY;
#pragma unroll
    for (int m = 0; m < M_EXP; ++m) if (m != i0 && l[m] > v1) { v1 = l[m]; i1 = m; }

    const float t = expf(v1 - v0);
    const float g0 = 1.0f / (1.0f + t);
    const float g1 = t * g0;

#pragma unroll
    for (int m = 0; m < M_EXP; ++m) out[OUT_GATES + b * M_EXP + m] = 0.0f;
    out[OUT_GATES + b * M_EXP + i0] = g0;
    out[OUT_GATES + b * M_EXP + i1] = g1;

    out[OUT_IDX + b * 2 + 0] = (float)i0;
    out[OUT_IDX + b * 2 + 1] = (float)i1;

    if (b == 0) out[OUT_LOSS] = 0.0f;
}

// ---------------------------------------------------------------------------
extern "C" void kernel_launch(void* const* d_in, const int* in_sizes, int n_in,
                              void* d_out, int out_size, void* d_ws, size_t ws_size,
                              hipStream_t stream) {
    const float* x        = (const float*)d_in[0];
    const float* degraded = (const float*)d_in[1];
    const float* w_fusion = (const float*)d_in[2];
    const float* b_fusion = (const float*)d_in[3];
    const float* w_gate   = (const float*)d_in[4];
    float* out = (float*)d_out;

    float* fused = (float*)d_ws;                          // 256*1024 f32 (1.0 MB, dense)
    float* pact2 = fused + (size_t)BATCH * D_X;           // 256*1792 f32 (1.84 MB)
    float* part  = pact2 + (size_t)BATCH * FDIM;          // 28*256*16 f32 (0.46 MB)

    // 1) deg-GEMM (blocks 0..223, hidden under pool) + pool (blocks 224..65759)
    pool_deggemm_kernel<<<NBLK_DGEMM + NBLK_POOL, 256, 0, stream>>>(x, degraded, w_fusion,
                                                                   fused, pact2);

    // 2) main GEMM K in [0,1024) + bias + gelu + gate partials: grid (8, 28)
    gemm_gate_kernel<<<dim3(BATCH / BM, FDIM / BN), 256, 0, stream>>>(fused, w_fusion, pact2,
                                                                     b_fusion, w_gate, part);

    // 3) finalize
    finalize_kernel<<<BATCH / 64, 64, 0, stream>>>(part, out);
}